// Round 1
// baseline (182.682 us; speedup 1.0000x reference)
//
#include <hip/hip_runtime.h>
#include <stdint.h>

#define B_ 4
#define S_ 2048
#define D_ 768
#define U_ 768

typedef __bf16 bf16x8 __attribute__((ext_vector_type(8)));
typedef float f32x4 __attribute__((ext_vector_type(4)));

#define AS1 __attribute__((address_space(1)))
#define AS3 __attribute__((address_space(3)))

__device__ __forceinline__ ushort f2bf(float f) {
    union { float f; uint32_t u; } v; v.f = f;
    uint32_t r = v.u + 0x7fffu + ((v.u >> 16) & 1u);
    return (ushort)(r >> 16);
}

__device__ __forceinline__ void gload_lds16(const void* gp, void* lp) {
    // width-16 global->LDS: LDS dest = wave-uniform base + lane*16
    __builtin_amdgcn_global_load_lds((AS1 void*)gp, (AS3 void*)lp, 16, 0, 0);
}

struct __align__(16) Smem {
    ushort A[128 * 32];   // 128 rows x 32 k, row-major, 64B/row
    ushort B[128 * 32];
};

// C[M,N] += A[M,Kd] @ Bt[N,Kd]^T.  A,Bt bf16 row-major (ld in elems).
// MODE 0: bf16 row-major out. MODE 1: bf16 transposed out into [B][U][S].
// MODE 2: f32 out scaled.      MODE 3: f32 out.
template <int MODE>
__device__ __forceinline__ void gemm128(
    Smem& sm,
    const ushort* __restrict__ A, int lda,
    const ushort* __restrict__ Bt, int ldb,
    void* __restrict__ Cp, int ldc, int Kd, float scale,
    int tile_y, int tile_x)
{
    const int tid = threadIdx.x;
    const int w = tid >> 6, l = tid & 63;
    const int lr = l & 15, lg = l >> 4;
    const int wr = (w >> 1) * 64, wc = (w & 1) * 64;
    const int row0 = tile_y * 128, col0 = tile_x * 128;

    f32x4 acc[4][4];
#pragma unroll
    for (int m = 0; m < 4; ++m)
#pragma unroll
        for (int n = 0; n < 4; ++n)
            acc[m][n] = (f32x4){0.f, 0.f, 0.f, 0.f};

    for (int k0 = 0; k0 < Kd; k0 += 32) {
        __syncthreads();  // prior reads of LDS done before overwrite
        // stage A tile: 8KB = 512 x 16B chunks; chunk c -> row c>>2, col (c&3)*8
#pragma unroll
        for (int i = 0; i < 2; ++i) {
            int chunk = w * 128 + i * 64 + l;
            int r = chunk >> 2, ce = (chunk & 3) * 8;
            gload_lds16(A + (size_t)(row0 + r) * lda + (k0 + ce),
                        sm.A + (w * 1024 + i * 512));
        }
#pragma unroll
        for (int i = 0; i < 2; ++i) {
            int chunk = w * 128 + i * 64 + l;
            int r = chunk >> 2, ce = (chunk & 3) * 8;
            gload_lds16(Bt + (size_t)(col0 + r) * ldb + (k0 + ce),
                        sm.B + (w * 1024 + i * 512));
        }
        __syncthreads();  // drains vmcnt(0) before barrier

        bf16x8 af[4], bfv[4];
#pragma unroll
        for (int m = 0; m < 4; ++m) {
            const ushort* p = sm.A + (wr + m * 16 + lr) * 32 + lg * 8;
            af[m] = *(const bf16x8*)p;
        }
#pragma unroll
        for (int n = 0; n < 4; ++n) {
            const ushort* p = sm.B + (wc + n * 16 + lr) * 32 + lg * 8;
            bfv[n] = *(const bf16x8*)p;
        }
#pragma unroll
        for (int m = 0; m < 4; ++m)
#pragma unroll
            for (int n = 0; n < 4; ++n)
                acc[m][n] = __builtin_amdgcn_mfma_f32_16x16x32_bf16(
                    af[m], bfv[n], acc[m][n], 0, 0, 0);
    }

    // epilogue: D frag mapping col = lane&15, row = (lane>>4)*4 + i
#pragma unroll
    for (int m = 0; m < 4; ++m) {
#pragma unroll
        for (int n = 0; n < 4; ++n) {
#pragma unroll
            for (int i = 0; i < 4; ++i) {
                int r = row0 + wr + m * 16 + lg * 4 + i;
                int c = col0 + wc + n * 16 + lr;
                float v = acc[m][n][i];
                if constexpr (MODE == 0) {
                    ((ushort*)Cp)[(size_t)r * ldc + c] = f2bf(v);
                } else if constexpr (MODE == 1) {
                    int b = r >> 11, s = r & 2047;  // rows are b*S + s
                    ((ushort*)Cp)[((size_t)b * U_ + c) * S_ + s] = f2bf(v);
                } else if constexpr (MODE == 2) {
                    ((float*)Cp)[(size_t)r * ldc + c] = v * scale;
                } else {
                    ((float*)Cp)[(size_t)r * ldc + c] = v;
                }
            }
        }
    }
}

__global__ void cast_x_kernel(const float4* __restrict__ in,
                              ushort4* __restrict__ out, int n4) {
    int i = blockIdx.x * 256 + threadIdx.x;
    if (i >= n4) return;
    float4 v = in[i];
    ushort4 o;
    o.x = f2bf(v.x); o.y = f2bf(v.y); o.z = f2bf(v.z); o.w = f2bf(v.w);
    out[i] = o;
}

__global__ void transpose_w_kernel(const float* __restrict__ Wq,
                                   const float* __restrict__ Wk,
                                   const float* __restrict__ Wv,
                                   ushort* __restrict__ Wt) {
    const float* W = blockIdx.z == 0 ? Wq : (blockIdx.z == 1 ? Wk : Wv);
    __shared__ float t[32][33];
    int x0 = blockIdx.x * 32, y0 = blockIdx.y * 32;
    int tx = threadIdx.x;
    for (int i = threadIdx.y; i < 32; i += 8)
        t[i][tx] = W[(size_t)(y0 + i) * U_ + (x0 + tx)];
    __syncthreads();
    ushort* Wtz = Wt + (size_t)blockIdx.z * U_ * D_;
    for (int i = threadIdx.y; i < 32; i += 8)
        Wtz[(size_t)(x0 + i) * D_ + (y0 + tx)] = f2bf(t[tx][i]);
}

__global__ __launch_bounds__(256) void proj_kernel(
    const ushort* __restrict__ xb, const ushort* __restrict__ Wt,
    ushort* __restrict__ Qb, ushort* __restrict__ Kb, ushort* __restrict__ Vt) {
    __shared__ Smem sm;
    int z = blockIdx.z;
    const ushort* Btz = Wt + (size_t)z * U_ * D_;
    if (z == 0)
        gemm128<0>(sm, xb, D_, Btz, D_, Qb, U_, D_, 1.f, blockIdx.y, blockIdx.x);
    else if (z == 1)
        gemm128<0>(sm, xb, D_, Btz, D_, Kb, U_, D_, 1.f, blockIdx.y, blockIdx.x);
    else
        gemm128<1>(sm, xb, D_, Btz, D_, Vt, 0, D_, 1.f, blockIdx.y, blockIdx.x);
}

__global__ __launch_bounds__(256) void scores_kernel(
    const ushort* __restrict__ Qb, const ushort* __restrict__ Kb,
    float* __restrict__ Sc, float scale, int scBatchStrideRows) {
    __shared__ Smem sm;
    int z = blockIdx.z;
    gemm128<2>(sm, Qb + (size_t)z * S_ * U_, U_, Kb + (size_t)z * S_ * U_, U_,
               Sc + (size_t)z * scBatchStrideRows * S_, S_, U_, scale,
               blockIdx.y, blockIdx.x);
}

__global__ __launch_bounds__(256) void softmax_kernel(
    const float* __restrict__ Sc, ushort* __restrict__ P) {
    size_t row = (size_t)blockIdx.y * gridDim.x + blockIdx.x;
    const float4* r4 = (const float4*)(Sc + row * S_);
    int t = threadIdx.x;
    int w = t >> 6, l = t & 63;
    float4 a = r4[t], b = r4[t + 256];
    float mx = fmaxf(fmaxf(fmaxf(a.x, a.y), fmaxf(a.z, a.w)),
                     fmaxf(fmaxf(b.x, b.y), fmaxf(b.z, b.w)));
#pragma unroll
    for (int off = 32; off; off >>= 1) mx = fmaxf(mx, __shfl_xor(mx, off));
    __shared__ float red[8];
    if (l == 0) red[w] = mx;
    __syncthreads();
    mx = fmaxf(fmaxf(red[0], red[1]), fmaxf(red[2], red[3]));
    float e[8];
    e[0] = __expf(a.x - mx); e[1] = __expf(a.y - mx);
    e[2] = __expf(a.z - mx); e[3] = __expf(a.w - mx);
    e[4] = __expf(b.x - mx); e[5] = __expf(b.y - mx);
    e[6] = __expf(b.z - mx); e[7] = __expf(b.w - mx);
    float s = e[0] + e[1] + e[2] + e[3] + e[4] + e[5] + e[6] + e[7];
#pragma unroll
    for (int off = 32; off; off >>= 1) s += __shfl_xor(s, off);
    if (l == 0) red[4 + w] = s;
    __syncthreads();
    float inv = 1.f / (red[4] + red[5] + red[6] + red[7]);
    ushort4* p4 = (ushort4*)(P + row * S_);
    ushort4 o1, o2;
    o1.x = f2bf(e[0] * inv); o1.y = f2bf(e[1] * inv);
    o1.z = f2bf(e[2] * inv); o1.w = f2bf(e[3] * inv);
    o2.x = f2bf(e[4] * inv); o2.y = f2bf(e[5] * inv);
    o2.z = f2bf(e[6] * inv); o2.w = f2bf(e[7] * inv);
    p4[t] = o1; p4[t + 256] = o2;
}

__global__ __launch_bounds__(256) void pv_kernel(
    const ushort* __restrict__ P, const ushort* __restrict__ Vt,
    float* __restrict__ out) {
    __shared__ Smem sm;
    int b = blockIdx.z;
    gemm128<3>(sm, P + (size_t)b * S_ * S_, S_, Vt + (size_t)b * U_ * S_, S_,
               out + (size_t)b * S_ * U_, U_, S_, 1.f, blockIdx.y, blockIdx.x);
}

extern "C" void kernel_launch(void* const* d_in, const int* in_sizes, int n_in,
                              void* d_out, int out_size, void* d_ws, size_t ws_size,
                              hipStream_t stream) {
    (void)in_sizes; (void)n_in; (void)out_size;
    const float* x = (const float*)d_in[0];
    const float* Wq = (const float*)d_in[1];
    const float* Wk = (const float*)d_in[2];
    const float* Wv = (const float*)d_in[3];
    float* out = (float*)d_out;

    char* ws = (char*)d_ws;
    size_t off = 0;
    auto alloc = [&](size_t bytes) -> void* {
        void* p = ws + off;
        off += (bytes + 255) & ~(size_t)255;
        return p;
    };
    ushort* xb = (ushort*)alloc((size_t)B_ * S_ * D_ * 2);
    ushort* Wt = (ushort*)alloc((size_t)3 * U_ * D_ * 2);
    ushort* Qb = (ushort*)alloc((size_t)B_ * S_ * U_ * 2);
    ushort* Kb = (ushort*)alloc((size_t)B_ * S_ * U_ * 2);
    ushort* Vt = (ushort*)alloc((size_t)B_ * S_ * U_ * 2);  // [B][U][S]
    ushort* P  = (ushort*)alloc((size_t)B_ * S_ * S_ * 2);
    // scores buffer: all-batch (67MB) if ws allows, else single-batch reused
    bool full = (ws_size - off) >= (size_t)B_ * S_ * S_ * 4 + 256;
    float* Sc = (float*)alloc(full ? (size_t)B_ * S_ * S_ * 4 : (size_t)S_ * S_ * 4);

    int n4 = B_ * S_ * D_ / 4;
    cast_x_kernel<<<(n4 + 255) / 256, 256, 0, stream>>>(
        (const float4*)x, (ushort4*)xb, n4);
    transpose_w_kernel<<<dim3(U_ / 32, D_ / 32, 3), dim3(32, 8), 0, stream>>>(
        Wq, Wk, Wv, Wt);
    proj_kernel<<<dim3(U_ / 128, B_ * S_ / 128, 3), 256, 0, stream>>>(
        xb, Wt, Qb, Kb, Vt);

    const float scale = 0.036084391824351615f;  // 1/sqrt(768)
    if (full) {
        scores_kernel<<<dim3(S_ / 128, S_ / 128, B_), 256, 0, stream>>>(
            Qb, Kb, Sc, scale, S_);
        softmax_kernel<<<dim3(S_, B_), 256, 0, stream>>>(Sc, P);
    } else {
        for (int b = 0; b < B_; ++b) {
            scores_kernel<<<dim3(S_ / 128, S_ / 128, 1), 256, 0, stream>>>(
                Qb + (size_t)b * S_ * U_, Kb + (size_t)b * S_ * U_, Sc, scale, 0);
            softmax_kernel<<<dim3(S_, 1), 256, 0, stream>>>(
                Sc, P + (size_t)b * S_ * S_);
        }
    }
    pv_kernel<<<dim3(U_ / 128, S_ / 128, B_), 256, 0, stream>>>(P, Vt, out);
}

// Round 2
// 163.251 us; speedup vs baseline: 1.1190x; 1.1190x over previous
//
#include <hip/hip_runtime.h>
#include <stdint.h>

#define B_ 4
#define S_ 2048
#define D_ 768
#define U_ 768

typedef __bf16 bf16x8 __attribute__((ext_vector_type(8)));
typedef float f32x4 __attribute__((ext_vector_type(4)));

#define AS1 __attribute__((address_space(1)))
#define AS3 __attribute__((address_space(3)))

#define BAR() __builtin_amdgcn_s_barrier()
#define WAITV6() asm volatile("s_waitcnt vmcnt(6)" ::: "memory")
#define WAITV0() asm volatile("s_waitcnt vmcnt(0)" ::: "memory")
#define PRIO(x) __builtin_amdgcn_s_setprio(x)

__device__ __forceinline__ ushort f2bf(float f) {
    union { float f; uint32_t u; } v; v.f = f;
    uint32_t r = v.u + 0x7fffu + ((v.u >> 16) & 1u);
    return (ushort)(r >> 16);
}

__device__ __forceinline__ void gload_lds16(const void* gp, void* lp) {
    // width-16 global->LDS: HW scatters to (wave-uniform lds base) + lane*16
    __builtin_amdgcn_global_load_lds((AS1 void*)gp, (AS3 void*)lp, 16, 0, 0);
}

// ============================================================================
// 256x256 8-phase pipelined GEMM (BK=64, 8 waves 2Mx4N, counted vmcnt(6),
// XOR-swizzled LDS, setprio around MFMA). C = A[M,K] @ Bt[N,K]^T.
// LDS: sA[2][256*64], sB[2][256*64] bf16 = 128 KiB (dynamic).
// Schedule per K-tile t (4 phases, 2 raw barriers each):
//   p0: read all B frags + A quad0 from buf[c]; stage A-pairs23 of t+1 -> buf[c^1]
//   p1: read A quad1; stage B-half0 of t+2 -> buf[c]   (B region of c freed at p0)
//   p2: read A quad2; stage B-half1 of t+2 -> buf[c]
//   p3: read A quad3; stage A-pairs01 of t+2 -> buf[c]; vmcnt(6) -> t+1 landed
// Per-wave in flight after tile-end wait = 6 loads = 3 half-tiles (t+2's).
// ============================================================================
template <int MODE>  // 0: bf16 out, 1: bf16 transposed to [B][U][S], 2: f32*scale
__device__ __forceinline__ void gemm256(
    ushort* sA, ushort* sB,
    const ushort* __restrict__ Ag, int lda,
    const ushort* __restrict__ Btg, int ldb,
    void* __restrict__ Cp, int ldc, int Kd, float scale,
    int ty, int tx)
{
    const int tid = threadIdx.x;
    const int l = tid & 63, w = tid >> 6;
    const int lr = l & 15, lg = l >> 4;
    const int wm = w >> 2, wn = w & 3;
    const int M0 = ty * 256, N0 = tx * 256;

    f32x4 acc[8][4];
#pragma unroll
    for (int m = 0; m < 8; ++m)
#pragma unroll
        for (int n = 0; n < 4; ++n)
            acc[m][n] = (f32x4){0.f, 0.f, 0.f, 0.f};

    const int NT = Kd >> 6;

    // stage A strip-pairs qp,qp+1 of K-tile kt into buf (2 gloads/thread)
    auto STA = [&](int buf, int qp, int kt) {
#pragma unroll
        for (int j = 0; j < 2; ++j) {
            int q = qp + j;
            int r0 = (w < 4) ? (q * 32 + w * 8) : (128 + q * 32 + (w - 4) * 8);
            int r = r0 + (l >> 3);
            int lc = ((l & 7) * 16) ^ ((r & 7) << 4);   // inverse-swizzled src col
            gload_lds16(Ag + (size_t)(M0 + r) * lda + kt * 64 + (lc >> 1),
                        sA + buf * 16384 + r0 * 64);
        }
    };
    // stage B half h (tile rows h*128..+128) of K-tile kt (2 gloads/thread)
    auto STB = [&](int buf, int h, int kt) {
#pragma unroll
        for (int j = 0; j < 2; ++j) {
            int r0 = h * 128 + j * 64 + w * 8;
            int r = r0 + (l >> 3);
            int lc = ((l & 7) * 16) ^ ((r & 7) << 4);
            gload_lds16(Btg + (size_t)(N0 + r) * ldb + kt * 64 + (lc >> 1),
                        sB + buf * 16384 + r0 * 64);
        }
    };

    bf16x8 afr[2][2], bfr[4][2];
    auto LDB = [&](int buf) {
#pragma unroll
        for (int nf = 0; nf < 4; ++nf)
#pragma unroll
            for (int ks = 0; ks < 2; ++ks) {
                int r = wn * 64 + nf * 16 + lr;
                int off = r * 128 + ((ks * 64 + lg * 16) ^ ((r & 7) << 4));
                bfr[nf][ks] = *(const bf16x8*)((const char*)(sB + buf * 16384) + off);
            }
    };
    auto LDA = [&](int buf, int q) {
#pragma unroll
        for (int j = 0; j < 2; ++j)
#pragma unroll
            for (int ks = 0; ks < 2; ++ks) {
                int r = wm * 128 + (2 * q + j) * 16 + lr;
                int off = r * 128 + ((ks * 64 + lg * 16) ^ ((r & 7) << 4));
                afr[j][ks] = *(const bf16x8*)((const char*)(sA + buf * 16384) + off);
            }
    };

#define MMQ(Q)                                                                 \
    PRIO(1);                                                                   \
    _Pragma("unroll")                                                          \
    for (int j = 0; j < 2; ++j)                                                \
        _Pragma("unroll")                                                      \
        for (int nf = 0; nf < 4; ++nf)                                         \
            _Pragma("unroll")                                                  \
            for (int ks = 0; ks < 2; ++ks)                                     \
                acc[2 * (Q) + j][nf] = __builtin_amdgcn_mfma_f32_16x16x32_bf16(\
                    afr[j][ks], bfr[nf][ks], acc[2 * (Q) + j][nf], 0, 0, 0);   \
    PRIO(0);

    // ---- prologue: tile0 full (8 loads) + tile1 B0,B1,pairs01 (6 loads) ----
    STA(0, 0, 0); STA(0, 2, 0); STB(0, 0, 0); STB(0, 1, 0);
    if (NT > 1) { STB(1, 0, 1); STB(1, 1, 1); STA(1, 0, 1); }
    if (NT > 1) { WAITV6(); } else { WAITV0(); }
    BAR();

    for (int t = 0; t < NT; ++t) {
        const int c = t & 1;
        // phase 0
        LDB(c); LDA(c, 0);
        if (t + 1 < NT) STA(c ^ 1, 2, t + 1);
        BAR();
        MMQ(0);
        BAR();
        // phase 1
        LDA(c, 1);
        if (t + 2 < NT) STB(c, 0, t + 2);
        BAR();
        MMQ(1);
        BAR();
        // phase 2
        LDA(c, 2);
        if (t + 2 < NT) STB(c, 1, t + 2);
        BAR();
        MMQ(2);
        BAR();
        // phase 3
        LDA(c, 3);
        if (t + 2 < NT) STA(c, 0, t + 2);
        BAR();
        MMQ(3);
        if (t + 2 < NT) { WAITV6(); } else { WAITV0(); }
        BAR();
    }
#undef MMQ

    // epilogue: C/D frag mapping col = lane&15, row = (lane>>4)*4 + i
#pragma unroll
    for (int mf = 0; mf < 8; ++mf) {
#pragma unroll
        for (int nf = 0; nf < 4; ++nf) {
#pragma unroll
            for (int i = 0; i < 4; ++i) {
                int r = M0 + wm * 128 + mf * 16 + lg * 4 + i;
                int c = N0 + wn * 64 + nf * 16 + lr;
                float v = acc[mf][nf][i];
                if constexpr (MODE == 0) {
                    ((ushort*)Cp)[(size_t)r * ldc + c] = f2bf(v);
                } else if constexpr (MODE == 1) {
                    int b = r >> 11, s = r & 2047;  // rows are b*S + s
                    ((ushort*)Cp)[((size_t)b * U_ + c) * S_ + s] = f2bf(v);
                } else {
                    ((float*)Cp)[(size_t)r * ldc + c] = v * scale;
                }
            }
        }
    }
}

__global__ __launch_bounds__(512) void proj256_kernel(
    const ushort* __restrict__ xb, const ushort* __restrict__ Wt,
    ushort* __restrict__ Qb, ushort* __restrict__ Kb, ushort* __restrict__ Vt) {
    extern __shared__ ushort sm[];
    const int nwg = gridDim.x;                       // 288, %8==0
    const int b0 = blockIdx.x;
    const int wg = (b0 & 7) * (nwg >> 3) + (b0 >> 3);  // XCD-contiguous
    const int tx = wg % 3, ty = (wg / 3) % 32, z = wg / 96;
    const ushort* Btz = Wt + (size_t)z * U_ * D_;
    ushort* sA = sm;
    ushort* sB = sm + 32768;
    if (z == 0)
        gemm256<0>(sA, sB, xb, D_, Btz, D_, Qb, U_, D_, 1.f, ty, tx);
    else if (z == 1)
        gemm256<0>(sA, sB, xb, D_, Btz, D_, Kb, U_, D_, 1.f, ty, tx);
    else
        gemm256<1>(sA, sB, xb, D_, Btz, D_, Vt, 0, D_, 1.f, ty, tx);
}

__global__ __launch_bounds__(512) void scores256_kernel(
    const ushort* __restrict__ Qb, const ushort* __restrict__ Kb,
    float* __restrict__ Sc, float scale) {
    extern __shared__ ushort sm[];
    const int nwg = gridDim.x;                       // 256 or 64, %8==0
    const int b0 = blockIdx.x;
    const int wg = (b0 & 7) * (nwg >> 3) + (b0 >> 3);
    const int tx = wg & 7, ty = (wg >> 3) & 7, z = wg >> 6;
    ushort* sA = sm;
    ushort* sB = sm + 32768;
    gemm256<2>(sA, sB, Qb + (size_t)z * S_ * U_, U_, Kb + (size_t)z * S_ * U_, U_,
               Sc + (size_t)z * S_ * S_, S_, U_, scale, ty, tx);
}

// ======================= round-1 kernels (unchanged) ========================

struct __align__(16) Smem {
    ushort A[128 * 32];
    ushort B[128 * 32];
};

template <int MODE>  // 3: f32 out
__device__ __forceinline__ void gemm128(
    Smem& sm,
    const ushort* __restrict__ A, int lda,
    const ushort* __restrict__ Bt, int ldb,
    void* __restrict__ Cp, int ldc, int Kd, float scale,
    int tile_y, int tile_x)
{
    const int tid = threadIdx.x;
    const int w = tid >> 6, l = tid & 63;
    const int lr = l & 15, lg = l >> 4;
    const int wr = (w >> 1) * 64, wc = (w & 1) * 64;
    const int row0 = tile_y * 128, col0 = tile_x * 128;

    f32x4 acc[4][4];
#pragma unroll
    for (int m = 0; m < 4; ++m)
#pragma unroll
        for (int n = 0; n < 4; ++n)
            acc[m][n] = (f32x4){0.f, 0.f, 0.f, 0.f};

    for (int k0 = 0; k0 < Kd; k0 += 32) {
        __syncthreads();
#pragma unroll
        for (int i = 0; i < 2; ++i) {
            int chunk = w * 128 + i * 64 + l;
            int r = chunk >> 2, ce = (chunk & 3) * 8;
            gload_lds16(A + (size_t)(row0 + r) * lda + (k0 + ce),
                        sm.A + (w * 1024 + i * 512));
        }
#pragma unroll
        for (int i = 0; i < 2; ++i) {
            int chunk = w * 128 + i * 64 + l;
            int r = chunk >> 2, ce = (chunk & 3) * 8;
            gload_lds16(Bt + (size_t)(col0 + r) * ldb + (k0 + ce),
                        sm.B + (w * 1024 + i * 512));
        }
        __syncthreads();

        bf16x8 af[4], bfv[4];
#pragma unroll
        for (int m = 0; m < 4; ++m)
            af[m] = *(const bf16x8*)(sm.A + (wr + m * 16 + lr) * 32 + lg * 8);
#pragma unroll
        for (int n = 0; n < 4; ++n)
            bfv[n] = *(const bf16x8*)(sm.B + (wc + n * 16 + lr) * 32 + lg * 8);
#pragma unroll
        for (int m = 0; m < 4; ++m)
#pragma unroll
            for (int n = 0; n < 4; ++n)
                acc[m][n] = __builtin_amdgcn_mfma_f32_16x16x32_bf16(
                    af[m], bfv[n], acc[m][n], 0, 0, 0);
    }

#pragma unroll
    for (int m = 0; m < 4; ++m)
#pragma unroll
        for (int n = 0; n < 4; ++n)
#pragma unroll
            for (int i = 0; i < 4; ++i) {
                int r = row0 + wr + m * 16 + lg * 4 + i;
                int c = col0 + wc + n * 16 + lr;
                ((float*)Cp)[(size_t)r * ldc + c] = acc[m][n][i];
            }
    (void)scale;
}

__global__ void cast_x_kernel(const float4* __restrict__ in,
                              ushort4* __restrict__ out, int n4) {
    int i = blockIdx.x * 256 + threadIdx.x;
    if (i >= n4) return;
    float4 v = in[i];
    ushort4 o;
    o.x = f2bf(v.x); o.y = f2bf(v.y); o.z = f2bf(v.z); o.w = f2bf(v.w);
    out[i] = o;
}

__global__ void transpose_w_kernel(const float* __restrict__ Wq,
                                   const float* __restrict__ Wk,
                                   const float* __restrict__ Wv,
                                   ushort* __restrict__ Wt) {
    const float* W = blockIdx.z == 0 ? Wq : (blockIdx.z == 1 ? Wk : Wv);
    __shared__ float t[32][33];
    int x0 = blockIdx.x * 32, y0 = blockIdx.y * 32;
    int tx = threadIdx.x;
    for (int i = threadIdx.y; i < 32; i += 8)
        t[i][tx] = W[(size_t)(y0 + i) * U_ + (x0 + tx)];
    __syncthreads();
    ushort* Wtz = Wt + (size_t)blockIdx.z * U_ * D_;
    for (int i = threadIdx.y; i < 32; i += 8)
        Wtz[(size_t)(x0 + i) * D_ + (y0 + tx)] = f2bf(t[tx][i]);
}

__global__ __launch_bounds__(256) void softmax_kernel(
    const float* __restrict__ Sc, ushort* __restrict__ P) {
    size_t row = (size_t)blockIdx.y * gridDim.x + blockIdx.x;
    const float4* r4 = (const float4*)(Sc + row * S_);
    int t = threadIdx.x;
    int w = t >> 6, l = t & 63;
    float4 a = r4[t], b = r4[t + 256];
    float mx = fmaxf(fmaxf(fmaxf(a.x, a.y), fmaxf(a.z, a.w)),
                     fmaxf(fmaxf(b.x, b.y), fmaxf(b.z, b.w)));
#pragma unroll
    for (int off = 32; off; off >>= 1) mx = fmaxf(mx, __shfl_xor(mx, off));
    __shared__ float red[8];
    if (l == 0) red[w] = mx;
    __syncthreads();
    mx = fmaxf(fmaxf(red[0], red[1]), fmaxf(red[2], red[3]));
    float e[8];
    e[0] = __expf(a.x - mx); e[1] = __expf(a.y - mx);
    e[2] = __expf(a.z - mx); e[3] = __expf(a.w - mx);
    e[4] = __expf(b.x - mx); e[5] = __expf(b.y - mx);
    e[6] = __expf(b.z - mx); e[7] = __expf(b.w - mx);
    float s = e[0] + e[1] + e[2] + e[3] + e[4] + e[5] + e[6] + e[7];
#pragma unroll
    for (int off = 32; off; off >>= 1) s += __shfl_xor(s, off);
    if (l == 0) red[4 + w] = s;
    __syncthreads();
    float inv = 1.f / (red[4] + red[5] + red[6] + red[7]);
    ushort4* p4 = (ushort4*)(P + row * S_);
    ushort4 o1, o2;
    o1.x = f2bf(e[0] * inv); o1.y = f2bf(e[1] * inv);
    o1.z = f2bf(e[2] * inv); o1.w = f2bf(e[3] * inv);
    o2.x = f2bf(e[4] * inv); o2.y = f2bf(e[5] * inv);
    o2.z = f2bf(e[6] * inv); o2.w = f2bf(e[7] * inv);
    p4[t] = o1; p4[t + 256] = o2;
}

__global__ __launch_bounds__(256) void pv_kernel(
    const ushort* __restrict__ P, const ushort* __restrict__ Vt,
    float* __restrict__ out) {
    __shared__ Smem sm;
    int b = blockIdx.z;
    gemm128<3>(sm, P + (size_t)b * S_ * S_, S_, Vt + (size_t)b * U_ * S_, S_,
               out + (size_t)b * S_ * U_, U_, S_, 1.f, blockIdx.y, blockIdx.x);
}

extern "C" void kernel_launch(void* const* d_in, const int* in_sizes, int n_in,
                              void* d_out, int out_size, void* d_ws, size_t ws_size,
                              hipStream_t stream) {
    (void)in_sizes; (void)n_in; (void)out_size;
    const float* x = (const float*)d_in[0];
    const float* Wq = (const float*)d_in[1];
    const float* Wk = (const float*)d_in[2];
    const float* Wv = (const float*)d_in[3];
    float* out = (float*)d_out;

    char* ws = (char*)d_ws;
    size_t off = 0;
    auto alloc = [&](size_t bytes) -> void* {
        void* p = ws + off;
        off += (bytes + 255) & ~(size_t)255;
        return p;
    };
    ushort* xb = (ushort*)alloc((size_t)B_ * S_ * D_ * 2);
    ushort* Wt = (ushort*)alloc((size_t)3 * U_ * D_ * 2);
    ushort* Qb = (ushort*)alloc((size_t)B_ * S_ * U_ * 2);
    ushort* Kb = (ushort*)alloc((size_t)B_ * S_ * U_ * 2);
    ushort* Vt = (ushort*)alloc((size_t)B_ * S_ * U_ * 2);  // [B][U][S]
    ushort* P  = (ushort*)alloc((size_t)B_ * S_ * S_ * 2);
    bool full = (ws_size - off) >= (size_t)B_ * S_ * S_ * 4 + 256;
    float* Sc = (float*)alloc(full ? (size_t)B_ * S_ * S_ * 4 : (size_t)S_ * S_ * 4);

    hipFuncSetAttribute(reinterpret_cast<const void*>(proj256_kernel),
                        hipFuncAttributeMaxDynamicSharedMemorySize, 131072);
    hipFuncSetAttribute(reinterpret_cast<const void*>(scores256_kernel),
                        hipFuncAttributeMaxDynamicSharedMemorySize, 131072);

    int n4 = B_ * S_ * D_ / 4;
    cast_x_kernel<<<(n4 + 255) / 256, 256, 0, stream>>>(
        (const float4*)x, (ushort4*)xb, n4);
    transpose_w_kernel<<<dim3(U_ / 32, D_ / 32, 3), dim3(32, 8), 0, stream>>>(
        Wq, Wk, Wv, Wt);
    proj256_kernel<<<288, 512, 131072, stream>>>(xb, Wt, Qb, Kb, Vt);

    const float scale = 0.036084391824351615f;  // 1/sqrt(768)
    if (full) {
        scores256_kernel<<<256, 512, 131072, stream>>>(Qb, Kb, Sc, scale);
        softmax_kernel<<<dim3(S_, B_), 256, 0, stream>>>(Sc, P);
    } else {
        for (int b = 0; b < B_; ++b) {
            scores256_kernel<<<64, 512, 131072, stream>>>(
                Qb + (size_t)b * S_ * U_, Kb + (size_t)b * S_ * U_, Sc, scale);
            softmax_kernel<<<dim3(S_, 1), 256, 0, stream>>>(
                Sc, P + (size_t)b * S_ * S_);
        }
    }
    pv_kernel<<<dim3(U_ / 128, S_ / 128, B_), 256, 0, stream>>>(P, Vt, out);
}

// Round 3
// 143.074 us; speedup vs baseline: 1.2768x; 1.1410x over previous
//
#include <hip/hip_runtime.h>
#include <stdint.h>

#define B_ 4
#define S_ 2048
#define D_ 768
#define U_ 768

typedef __bf16 bf16x8 __attribute__((ext_vector_type(8)));
typedef float f32x4 __attribute__((ext_vector_type(4)));

#define AS1 __attribute__((address_space(1)))
#define AS3 __attribute__((address_space(3)))

#define BAR() __builtin_amdgcn_s_barrier()
#define WAITV6() asm volatile("s_waitcnt vmcnt(6)" ::: "memory")
#define WAITV4() asm volatile("s_waitcnt vmcnt(4)" ::: "memory")
#define WAITV0() asm volatile("s_waitcnt vmcnt(0)" ::: "memory")
#define PRIO(x) __builtin_amdgcn_s_setprio(x)

__device__ __forceinline__ ushort f2bf(float f) {
    union { float f; uint32_t u; } v; v.f = f;
    uint32_t r = v.u + 0x7fffu + ((v.u >> 16) & 1u);
    return (ushort)(r >> 16);
}

__device__ __forceinline__ void gload_lds16(const void* gp, void* lp) {
    // width-16 global->LDS: HW scatters to (wave-uniform lds base) + lane*16
    __builtin_amdgcn_global_load_lds((AS1 void*)gp, (AS3 void*)lp, 16, 0, 0);
}

// ============================================================================
// BM x 256 8-phase pipelined GEMM (BK=64, 8 waves, counted vmcnt, XOR-swizzled
// LDS, setprio around MFMA). C = A[M,K] @ Bt[N,K]^T. BM in {128, 256}.
// Waves 2Mx4N; per-wave output (BM/2) x 64.
// LDS: sA[2][BM*64], sB[2][256*64] bf16 (96 KiB / 128 KiB dynamic).
// Per K-tile t, 4 phases x {ds-read quad | stage | BAR | MFMA | BAR}:
//   BM=256: p0 stages A-half1(t+1); p1/p2 stage B0/B1(t+2); p3 stages
//           A-half0(t+2); tile-end vmcnt(6) (leaves B0,B1,Ah0 of t+2).
//   BM=128: p0 stages A(t+1) fully (2 loads); p1/p2 stage B0/B1(t+2);
//           tile-end vmcnt(4) (leaves B0,B1 of t+2).
// ============================================================================
template <int BM, int MODE>  // MODE 0: bf16 out, 1: bf16 -> [B][U][S], 2: f32*scale
__device__ __forceinline__ void gemmT(
    ushort* sm,
    const ushort* __restrict__ Ag, int lda,
    const ushort* __restrict__ Btg, int ldb,
    void* __restrict__ Cp, int ldc, int Kd, float scale,
    int ty, int tx)
{
    constexpr int MJ = BM / 128;       // M-frags per phase
    constexpr int ABUF = BM * 64;      // elems per A buffer
    ushort* sA = sm;
    ushort* sB = sm + 2 * ABUF;

    const int tid = threadIdx.x;
    const int l = tid & 63, w = tid >> 6;
    const int lr = l & 15, lg = l >> 4;
    const int wm = w >> 2, wn = w & 3;
    const int M0 = ty * BM, N0 = tx * 256;

    f32x4 acc[4 * MJ][4];
#pragma unroll
    for (int m = 0; m < 4 * MJ; ++m)
#pragma unroll
        for (int n = 0; n < 4; ++n)
            acc[m][n] = (f32x4){0.f, 0.f, 0.f, 0.f};

    const int NT = Kd >> 6;

    // BM=256: stage A strip-pairs qp,qp+1 of K-tile kt (2 gloads/thread)
    auto STA256 = [&](int buf, int qp, int kt) {
#pragma unroll
        for (int j = 0; j < 2; ++j) {
            int q = qp + j;
            int r0 = (w < 4) ? (q * 32 + w * 8) : (128 + q * 32 + (w - 4) * 8);
            int r = r0 + (l >> 3);
            int lc = ((l & 7) * 16) ^ ((r & 7) << 4);   // inverse-swizzled src col
            gload_lds16(Ag + (size_t)(M0 + r) * lda + kt * 64 + (lc >> 1),
                        sA + buf * ABUF + r0 * 64);
        }
    };
    // BM=128: stage full A tile of K-tile kt (2 gloads/thread)
    auto STA128 = [&](int buf, int kt) {
#pragma unroll
        for (int j = 0; j < 2; ++j) {
            int r0 = w * 16 + j * 8;
            int r = r0 + (l >> 3);
            int lc = ((l & 7) * 16) ^ ((r & 7) << 4);
            gload_lds16(Ag + (size_t)(M0 + r) * lda + kt * 64 + (lc >> 1),
                        sA + buf * ABUF + r0 * 64);
        }
    };
    // stage B half h (tile rows h*128..+128) of K-tile kt (2 gloads/thread)
    auto STB = [&](int buf, int h, int kt) {
#pragma unroll
        for (int j = 0; j < 2; ++j) {
            int r0 = h * 128 + j * 64 + w * 8;
            int r = r0 + (l >> 3);
            int lc = ((l & 7) * 16) ^ ((r & 7) << 4);
            gload_lds16(Btg + (size_t)(N0 + r) * ldb + kt * 64 + (lc >> 1),
                        sB + buf * 16384 + r0 * 64);
        }
    };

    bf16x8 afr[MJ][2], bfr[4][2];
    auto LDB = [&](int buf) {
#pragma unroll
        for (int nf = 0; nf < 4; ++nf)
#pragma unroll
            for (int ks = 0; ks < 2; ++ks) {
                int r = wn * 64 + nf * 16 + lr;
                int off = r * 128 + ((ks * 64 + lg * 16) ^ ((r & 7) << 4));
                bfr[nf][ks] = *(const bf16x8*)((const char*)(sB + buf * 16384) + off);
            }
    };
    auto LDA = [&](int buf, int q) {
#pragma unroll
        for (int j = 0; j < MJ; ++j)
#pragma unroll
            for (int ks = 0; ks < 2; ++ks) {
                int r = wm * (BM / 2) + (MJ * q + j) * 16 + lr;
                int off = r * 128 + ((ks * 64 + lg * 16) ^ ((r & 7) << 4));
                afr[j][ks] = *(const bf16x8*)((const char*)(sA + buf * ABUF) + off);
            }
    };

#define MMQ(Q)                                                                 \
    PRIO(1);                                                                   \
    _Pragma("unroll")                                                          \
    for (int j = 0; j < MJ; ++j)                                               \
        _Pragma("unroll")                                                      \
        for (int nf = 0; nf < 4; ++nf)                                         \
            _Pragma("unroll")                                                  \
            for (int ks = 0; ks < 2; ++ks)                                     \
                acc[MJ * (Q) + j][nf] = __builtin_amdgcn_mfma_f32_16x16x32_bf16(\
                    afr[j][ks], bfr[nf][ks], acc[MJ * (Q) + j][nf], 0, 0, 0);  \
    PRIO(0);

    // ---- prologue: tile0 fully; tile1's B (and, for BM=256, A-half0) ----
    if constexpr (BM == 256) { STA256(0, 0, 0); STA256(0, 2, 0); }
    else                     { STA128(0, 0); }
    STB(0, 0, 0); STB(0, 1, 0);
    if (NT > 1) {
        STB(1, 0, 1); STB(1, 1, 1);
        if constexpr (BM == 256) STA256(1, 0, 1);
        if constexpr (BM == 256) { WAITV6(); } else { WAITV4(); }
    } else {
        WAITV0();
    }
    BAR();

    for (int t = 0; t < NT; ++t) {
        const int c = t & 1;
        // phase 0
        LDB(c); LDA(c, 0);
        if (t + 1 < NT) {
            if constexpr (BM == 256) STA256(c ^ 1, 2, t + 1);
            else                     STA128(c ^ 1, t + 1);
        }
        BAR();
        MMQ(0);
        BAR();
        // phase 1
        LDA(c, 1);
        if (t + 2 < NT) STB(c, 0, t + 2);
        BAR();
        MMQ(1);
        BAR();
        // phase 2
        LDA(c, 2);
        if (t + 2 < NT) STB(c, 1, t + 2);
        BAR();
        MMQ(2);
        BAR();
        // phase 3
        LDA(c, 3);
        if constexpr (BM == 256) { if (t + 2 < NT) STA256(c, 0, t + 2); }
        BAR();
        MMQ(3);
        if (t + 2 < NT) {
            if constexpr (BM == 256) { WAITV6(); } else { WAITV4(); }
        } else {
            WAITV0();
        }
        BAR();
    }
#undef MMQ

    // epilogue: C/D frag mapping col = lane&15, row = (lane>>4)*4 + i
#pragma unroll
    for (int mf = 0; mf < 4 * MJ; ++mf) {
#pragma unroll
        for (int nf = 0; nf < 4; ++nf) {
#pragma unroll
            for (int i = 0; i < 4; ++i) {
                int r = M0 + wm * (BM / 2) + mf * 16 + lg * 4 + i;
                int c = N0 + wn * 64 + nf * 16 + lr;
                float v = acc[mf][nf][i];
                if constexpr (MODE == 0) {
                    ((ushort*)Cp)[(size_t)r * ldc + c] = f2bf(v);
                } else if constexpr (MODE == 1) {
                    int b = r >> 11, s = r & 2047;  // rows are b*S + s
                    ((ushort*)Cp)[((size_t)b * U_ + c) * S_ + s] = f2bf(v);
                } else {
                    ((float*)Cp)[(size_t)r * ldc + c] = v * scale;
                }
            }
        }
    }
}

__global__ __launch_bounds__(512) void proj_kernel(
    const ushort* __restrict__ xb, const ushort* __restrict__ Wt,
    ushort* __restrict__ Qb, ushort* __restrict__ Kb, ushort* __restrict__ Vt) {
    extern __shared__ ushort sm[];
    const int nwg = 576;                             // 64 ty x 3 tx x 3 z
    const int b0 = blockIdx.x;
    const int wg = (b0 & 7) * (nwg >> 3) + (b0 >> 3);  // XCD-contiguous
    const int z = wg / 192, rem = wg % 192;
    const int ty = rem / 3, tx = rem % 3;
    const ushort* Btz = Wt + (size_t)z * U_ * D_;
    if (z == 0)
        gemmT<128, 0>(sm, xb, D_, Btz, D_, Qb, U_, D_, 1.f, ty, tx);
    else if (z == 1)
        gemmT<128, 0>(sm, xb, D_, Btz, D_, Kb, U_, D_, 1.f, ty, tx);
    else
        gemmT<128, 1>(sm, xb, D_, Btz, D_, Vt, 0, D_, 1.f, ty, tx);
}

__global__ __launch_bounds__(512) void scores_kernel(
    const ushort* __restrict__ Qb, const ushort* __restrict__ Kb,
    float* __restrict__ Sc, float scale) {
    extern __shared__ ushort sm[];
    const int nwg = gridDim.x;                       // 256 or 64, %8==0
    const int b0 = blockIdx.x;
    const int wg = (b0 & 7) * (nwg >> 3) + (b0 >> 3);
    const int tx = wg & 7, ty = (wg >> 3) & 7, z = wg >> 6;
    gemmT<256, 2>(sm, Qb + (size_t)z * S_ * U_, U_, Kb + (size_t)z * S_ * U_, U_,
                  Sc + (size_t)z * S_ * S_, S_, U_, scale, ty, tx);
}

__global__ __launch_bounds__(512) void pv_kernel(
    const ushort* __restrict__ P, const ushort* __restrict__ Vt,
    float* __restrict__ out) {
    extern __shared__ ushort sm[];
    const int nwg = 192;                             // 16 ty x 3 tx x 4 z
    const int b0 = blockIdx.x;
    const int wg = (b0 & 7) * (nwg >> 3) + (b0 >> 3);
    const int z = wg / 48, rem = wg % 48;
    const int ty = rem / 3, tx = rem % 3;
    gemmT<128, 2>(sm, P + (size_t)z * S_ * S_, S_, Vt + (size_t)z * U_ * S_, S_,
                  out + (size_t)z * S_ * U_, U_, S_, 1.f, ty, tx);
}

// ======================= small helper kernels ========================

__global__ void cast_x_kernel(const float4* __restrict__ in,
                              ushort4* __restrict__ out, int n4) {
    int i = blockIdx.x * 256 + threadIdx.x;
    if (i >= n4) return;
    float4 v = in[i];
    ushort4 o;
    o.x = f2bf(v.x); o.y = f2bf(v.y); o.z = f2bf(v.z); o.w = f2bf(v.w);
    out[i] = o;
}

__global__ void transpose_w_kernel(const float* __restrict__ Wq,
                                   const float* __restrict__ Wk,
                                   const float* __restrict__ Wv,
                                   ushort* __restrict__ Wt) {
    const float* W = blockIdx.z == 0 ? Wq : (blockIdx.z == 1 ? Wk : Wv);
    __shared__ float t[32][33];
    int x0 = blockIdx.x * 32, y0 = blockIdx.y * 32;
    int tx = threadIdx.x;
    for (int i = threadIdx.y; i < 32; i += 8)
        t[i][tx] = W[(size_t)(y0 + i) * U_ + (x0 + tx)];
    __syncthreads();
    ushort* Wtz = Wt + (size_t)blockIdx.z * U_ * D_;
    for (int i = threadIdx.y; i < 32; i += 8)
        Wtz[(size_t)(x0 + i) * D_ + (y0 + tx)] = f2bf(t[tx][i]);
}

__global__ __launch_bounds__(256) void softmax_kernel(
    const float* __restrict__ Sc, ushort* __restrict__ P) {
    size_t row = (size_t)blockIdx.y * gridDim.x + blockIdx.x;
    const float4* r4 = (const float4*)(Sc + row * S_);
    int t = threadIdx.x;
    int w = t >> 6, l = t & 63;
    float4 a = r4[t], b = r4[t + 256];
    float mx = fmaxf(fmaxf(fmaxf(a.x, a.y), fmaxf(a.z, a.w)),
                     fmaxf(fmaxf(b.x, b.y), fmaxf(b.z, b.w)));
#pragma unroll
    for (int off = 32; off; off >>= 1) mx = fmaxf(mx, __shfl_xor(mx, off));
    __shared__ float red[8];
    if (l == 0) red[w] = mx;
    __syncthreads();
    mx = fmaxf(fmaxf(red[0], red[1]), fmaxf(red[2], red[3]));
    float e[8];
    e[0] = __expf(a.x - mx); e[1] = __expf(a.y - mx);
    e[2] = __expf(a.z - mx); e[3] = __expf(a.w - mx);
    e[4] = __expf(b.x - mx); e[5] = __expf(b.y - mx);
    e[6] = __expf(b.z - mx); e[7] = __expf(b.w - mx);
    float s = e[0] + e[1] + e[2] + e[3] + e[4] + e[5] + e[6] + e[7];
#pragma unroll
    for (int off = 32; off; off >>= 1) s += __shfl_xor(s, off);
    if (l == 0) red[4 + w] = s;
    __syncthreads();
    float inv = 1.f / (red[4] + red[5] + red[6] + red[7]);
    ushort4* p4 = (ushort4*)(P + row * S_);
    ushort4 o1, o2;
    o1.x = f2bf(e[0] * inv); o1.y = f2bf(e[1] * inv);
    o1.z = f2bf(e[2] * inv); o1.w = f2bf(e[3] * inv);
    o2.x = f2bf(e[4] * inv); o2.y = f2bf(e[5] * inv);
    o2.z = f2bf(e[6] * inv); o2.w = f2bf(e[7] * inv);
    p4[t] = o1; p4[t + 256] = o2;
}

extern "C" void kernel_launch(void* const* d_in, const int* in_sizes, int n_in,
                              void* d_out, int out_size, void* d_ws, size_t ws_size,
                              hipStream_t stream) {
    (void)in_sizes; (void)n_in; (void)out_size;
    const float* x = (const float*)d_in[0];
    const float* Wq = (const float*)d_in[1];
    const float* Wk = (const float*)d_in[2];
    const float* Wv = (const float*)d_in[3];
    float* out = (float*)d_out;

    char* ws = (char*)d_ws;
    size_t off = 0;
    auto alloc = [&](size_t bytes) -> void* {
        void* p = ws + off;
        off += (bytes + 255) & ~(size_t)255;
        return p;
    };
    ushort* xb = (ushort*)alloc((size_t)B_ * S_ * D_ * 2);
    ushort* Wt = (ushort*)alloc((size_t)3 * U_ * D_ * 2);
    ushort* Qb = (ushort*)alloc((size_t)B_ * S_ * U_ * 2);
    ushort* Kb = (ushort*)alloc((size_t)B_ * S_ * U_ * 2);
    ushort* Vt = (ushort*)alloc((size_t)B_ * S_ * U_ * 2);  // [B][U][S]
    ushort* P  = (ushort*)alloc((size_t)B_ * S_ * S_ * 2);
    bool full = (ws_size - off) >= (size_t)B_ * S_ * S_ * 4 + 256;
    float* Sc = (float*)alloc(full ? (size_t)B_ * S_ * S_ * 4 : (size_t)S_ * S_ * 4);

    hipFuncSetAttribute(reinterpret_cast<const void*>(proj_kernel),
                        hipFuncAttributeMaxDynamicSharedMemorySize, 131072);
    hipFuncSetAttribute(reinterpret_cast<const void*>(scores_kernel),
                        hipFuncAttributeMaxDynamicSharedMemorySize, 131072);
    hipFuncSetAttribute(reinterpret_cast<const void*>(pv_kernel),
                        hipFuncAttributeMaxDynamicSharedMemorySize, 131072);

    int n4 = B_ * S_ * D_ / 4;
    cast_x_kernel<<<(n4 + 255) / 256, 256, 0, stream>>>(
        (const float4*)x, (ushort4*)xb, n4);
    transpose_w_kernel<<<dim3(U_ / 32, D_ / 32, 3), dim3(32, 8), 0, stream>>>(
        Wq, Wk, Wv, Wt);
    proj_kernel<<<576, 512, 98304, stream>>>(xb, Wt, Qb, Kb, Vt);

    const float scale = 0.036084391824351615f;  // 1/sqrt(768)
    if (full) {
        scores_kernel<<<256, 512, 131072, stream>>>(Qb, Kb, Sc, scale);
        softmax_kernel<<<dim3(S_, B_), 256, 0, stream>>>(Sc, P);
    } else {
        for (int b = 0; b < B_; ++b) {
            scores_kernel<<<64, 512, 131072, stream>>>(
                Qb + (size_t)b * S_ * U_, Kb + (size_t)b * S_ * U_, Sc, scale);
            softmax_kernel<<<dim3(S_, 1), 256, 0, stream>>>(
                Sc, P + (size_t)b * S_ * S_);
        }
    }
    pv_kernel<<<192, 512, 98304, stream>>>(P, Vt, out);
}